// Round 5
// baseline (345.707 us; speedup 1.0000x reference)
//
#include <hip/hip_runtime.h>
#include <math.h>

#define DD    64
#define TT    256
#define NROW  4096
#define BLK   512
#define GRID  256          // NROW/16 row-tiles, 1 block/CU, 8 waves = 2/SIMD

typedef __attribute__((ext_vector_type(8))) short  short8;
typedef __attribute__((ext_vector_type(4))) float  f32x4;

// Raw workgroup barrier: LDS visibility only (lgkmcnt), no vmcnt drain.
// Global loads/stores ride across (T4). "memory" clobber orders the ds ops;
// sched_barrier(0) pins MFMA/VALU from crossing (rule #18).
#define BARRIER() do {                                        \
    asm volatile("s_waitcnt lgkmcnt(0)" ::: "memory");        \
    __builtin_amdgcn_sched_barrier(0);                        \
    __builtin_amdgcn_s_barrier();                             \
    __builtin_amdgcn_sched_barrier(0);                        \
  } while (0)

__device__ __forceinline__ unsigned short f2bf(float f) {
  unsigned u = __builtin_bit_cast(unsigned, f);
  u += 0x7fffu + ((u >> 16) & 1u);          // round-to-nearest-even
  return (unsigned short)(u >> 16);
}

__device__ __forceinline__ unsigned long long pack4(float4 v) {
  return (unsigned long long)f2bf(v.x)
       | ((unsigned long long)f2bf(v.y) << 16)
       | ((unsigned long long)f2bf(v.z) << 32)
       | ((unsigned long long)f2bf(v.w) << 48);
}

__device__ __forceinline__ short8 load_wfrag(const float* p) {
  float4 a = *(const float4*)p;
  float4 b = *(const float4*)(p + 4);
  short8 r;
  r[0] = (short)f2bf(a.x); r[1] = (short)f2bf(a.y);
  r[2] = (short)f2bf(a.z); r[3] = (short)f2bf(a.w);
  r[4] = (short)f2bf(b.x); r[5] = (short)f2bf(b.y);
  r[6] = (short)f2bf(b.z); r[7] = (short)f2bf(b.w);
  return r;
}

__device__ __forceinline__ float fsigmoid(float x) {
  return __builtin_amdgcn_rcpf(1.0f + __expf(-x));
}
__device__ __forceinline__ float ftanh(float x) {
  return 1.0f - 2.0f * __builtin_amdgcn_rcpf(1.0f + __expf(2.0f * x));
}
// A&S 7.1.26 erf, max abs err 1.5e-7
__device__ __forceinline__ float ferf(float x) {
  float ax = fabsf(x);
  float t  = __builtin_amdgcn_rcpf(fmaf(0.3275911f, ax, 1.0f));
  float p  = fmaf(1.061405429f, t, -1.453152027f);
  p = fmaf(p, t, 1.421413741f);
  p = fmaf(p, t, -0.284496736f);
  p = fmaf(p, t, 0.254829592f);
  p = p * t;
  float y = 1.0f - p * __expf(-ax * ax);
  return copysignf(y, x);
}

// bias_t[t][j] = msg_b[j] + sum_d cos(t*freq[d]+phase[d]) * msg_W[j][128+d]
__global__ void bias_kernel(const float* __restrict__ msg_W,
                            const float* __restrict__ msg_b,
                            const float* __restrict__ freq,
                            const float* __restrict__ phase,
                            float* __restrict__ bias_t) {
  __shared__ float teL[DD];
  const int t = blockIdx.x;
  const int j = threadIdx.x;
  teL[j] = cosf(fmaf((float)t, freq[j], phase[j]));
  __syncthreads();
  float acc = msg_b[j];
  const float* wrow = msg_W + j * 192 + 128;
  #pragma unroll 8
  for (int k = 0; k < DD; ++k) acc = fmaf(teL[k], wrow[k], acc);
  bias_t[t * DD + j] = acc;
}

__launch_bounds__(BLK, 1)
__global__ void scan5(const float* __restrict__ x,
                      const int*   __restrict__ mask,
                      const float* __restrict__ msg_W,
                      const float* __restrict__ W_ih,
                      const float* __restrict__ W_hh,
                      const float* __restrict__ b_ih,
                      const float* __restrict__ b_hh,
                      const float* __restrict__ bias_t,
                      float* __restrict__ out) {
  // bf16 tiles: stride 72 shorts (144 B) -> <=2-way banks on b128 frag reads
  __shared__ alignas(16) unsigned short xs[2][16 * 72];  // double-buffered x tile
  __shared__ alignas(16) unsigned short ss[16 * 72];
  __shared__ alignas(16) unsigned short ms[16 * 72];
  __shared__ alignas(16) float s0a[16 * 68];   // init-mean scratch / s0 handoff
  __shared__ alignas(16) float ghl[16 * 260];  // gh transfer [rr][n*4+{r,z,n,pad}]
  __shared__ int tr_lds[TT + 2];

  const int tid  = threadIdx.x;
  const int lane = tid & 63;
  const int wv   = tid >> 6;
  const int grp  = wv >> 2;        // 0: msg/gi/gates chain, 1: gh + staging
  const int w4   = wv & 3;
  const int col  = lane & 15;
  const int kh   = lane >> 4;
  const int n    = w4 * 16 + col;  // output column this lane owns
  const int row0 = blockIdx.x * 16;

  if (tid < TT) tr_lds[tid] = tid * mask[tid];
  else if (tid < TT + 2) tr_lds[tid] = 0;

  // ---- group-specific weight fragments (registers, one-time) ----
  short8 wm[4], wi[3][2], wh[3][2];
  float bsum01[2] = {0.f, 0.f}, bih2 = 0.f, bhh2 = 0.f;
  if (grp == 0) {
    const float* mrow = msg_W + (size_t)n * 192;
    #pragma unroll
    for (int kf = 0; kf < 4; ++kf) wm[kf] = load_wfrag(mrow + kf * 32 + kh * 8);
    #pragma unroll
    for (int p = 0; p < 3; ++p) {
      const float* irow = W_ih + (size_t)(p * 64 + n) * 64;
      #pragma unroll
      for (int kf = 0; kf < 2; ++kf) wi[p][kf] = load_wfrag(irow + kf * 32 + kh * 8);
    }
    bsum01[0] = b_ih[n]      + b_hh[n];        // r-gate combined bias
    bsum01[1] = b_ih[64 + n] + b_hh[64 + n];   // z-gate combined bias
    bih2 = b_ih[128 + n];
    bhh2 = b_hh[128 + n];
  } else {
    #pragma unroll
    for (int p = 0; p < 3; ++p) {
      const float* hrow = W_hh + (size_t)(p * 64 + n) * 64;
      #pragma unroll
      for (int kf = 0; kf < 2; ++kf) wh[p][kf] = load_wfrag(hrow + kf * 32 + kh * 8);
    }
  }

  // ---- s0 = mean over t (512 threads: 2 time-halves x 16 rows x 16 float4) ----
  {
    const int half = tid >> 8, rem = tid & 255;
    const int fr = rem >> 4, fd = (rem & 15) * 4;
    const float* px = x + ((size_t)half * 128) * (NROW * DD)
                        + (size_t)(row0 + fr) * DD + fd;
    float4 acc = {0.f, 0.f, 0.f, 0.f};
    #pragma unroll 4
    for (int tl = 0; tl < 128; ++tl) {
      float4 v = *(const float4*)(px + (size_t)tl * (NROW * DD));
      acc.x += v.x; acc.y += v.y; acc.z += v.z; acc.w += v.w;
    }
    float* dst = (half == 0) ? &s0a[fr * 68 + fd] : &ghl[fr * 68 + fd];
    *(float4*)dst = acc;
  }
  __syncthreads();
  if (tid < 256) {
    const int fr = tid >> 4, fd = (tid & 15) * 4;
    float4 a = *(const float4*)&s0a[fr * 68 + fd];
    float4 b = *(const float4*)&ghl[fr * 68 + fd];
    const float inv = 1.0f / 256.0f;
    float4 m = { (a.x + b.x) * inv, (a.y + b.y) * inv,
                 (a.z + b.z) * inv, (a.w + b.w) * inv };
    *(float4*)&s0a[fr * 68 + fd] = m;
    *(unsigned long long*)&ss[fr * 72 + fd] = pack4(m);
    float4 xv0 = *(const float4*)(x + (size_t)(row0 + fr) * DD + fd);  // tr[0]=0
    *(unsigned long long*)&xs[0][fr * 72 + fd] = pack4(xv0);
  }
  __syncthreads();

  // G0: fp32 state registers + first msg bias
  float s_reg[4] = {0.f, 0.f, 0.f, 0.f};
  float btc = 0.f;
  if (grp == 0) {
    #pragma unroll
    for (int i = 0; i < 4; ++i) s_reg[i] = s0a[(kh * 4 + i) * 68 + n];
    btc = bias_t[n];                 // bias for t=0 (tr[0]=0)
    __builtin_amdgcn_s_setprio(1);   // critical-chain waves get priority
  }

  // G1 staging map: 256 threads cover 16 rows x 16 float4
  const int t1  = tid & 255;
  const int fr1 = t1 >> 4;
  const int fd1 = (t1 & 15) * 4;
  // preload x(tr[1]) — consumed at phase1(0) xs write (full-step cover thereafter)
  float4 xv = {0.f, 0.f, 0.f, 0.f};
  if (grp == 1)
    xv = *(const float4*)(x + ((size_t)tr_lds[1] * NROW + row0 + fr1) * DD + fd1);

  for (int t = 0; t < TT; ++t) {
    // ================= PHASE 1 =================
    if (grp == 0) {
      // msg = GELU( x-part + s-part + bias_t )  (two parallel 2-chains)
      const unsigned short* ax = &xs[t & 1][(lane & 15) * 72];
      const unsigned short* as = &ss[(lane & 15) * 72];
      short8 xa0 = *(const short8*)(ax + kh * 8);
      short8 xa1 = *(const short8*)(ax + 32 + kh * 8);
      short8 sa0 = *(const short8*)(as + kh * 8);
      short8 sa1 = *(const short8*)(as + 32 + kh * 8);
      // prefetch next step's bias (L2-hot; consumed next phase1)
      float btn = 0.f;
      if (t + 1 < TT) btn = bias_t[tr_lds[t + 1] * DD + n];
      f32x4 amx = {0.f, 0.f, 0.f, 0.f};
      amx = __builtin_amdgcn_mfma_f32_16x16x32_bf16(xa0, wm[0], amx, 0, 0, 0);
      amx = __builtin_amdgcn_mfma_f32_16x16x32_bf16(xa1, wm[1], amx, 0, 0, 0);
      f32x4 ams = {0.f, 0.f, 0.f, 0.f};
      ams = __builtin_amdgcn_mfma_f32_16x16x32_bf16(sa0, wm[2], ams, 0, 0, 0);
      ams = __builtin_amdgcn_mfma_f32_16x16x32_bf16(sa1, wm[3], ams, 0, 0, 0);
      #pragma unroll
      for (int i = 0; i < 4; ++i) {
        float a = amx[i] + ams[i] + btc;
        float g = 0.5f * a * (1.0f + ferf(a * 0.70710678118654752f));
        ms[(kh * 4 + i) * 72 + n] = f2bf(g);
      }
      btc = btn;
    } else {
      // stage xs for t+1 from xv (loaded a full step ago), then refill xv for t+2
      if (t + 1 < TT)
        *(unsigned long long*)&xs[(t + 1) & 1][fr1 * 72 + fd1] = pack4(xv);
      if (t + 2 < TT)
        xv = *(const float4*)(x + ((size_t)tr_lds[t + 2] * NROW + row0 + fr1) * DD + fd1);
      // gh = s @ W_hh^T
      const unsigned short* as = &ss[(lane & 15) * 72];
      short8 sa0 = *(const short8*)(as + kh * 8);
      short8 sa1 = *(const short8*)(as + 32 + kh * 8);
      f32x4 agh[3];
      #pragma unroll
      for (int p = 0; p < 3; ++p) {
        f32x4 c = {0.f, 0.f, 0.f, 0.f};
        c = __builtin_amdgcn_mfma_f32_16x16x32_bf16(sa0, wh[p][0], c, 0, 0, 0);
        c = __builtin_amdgcn_mfma_f32_16x16x32_bf16(sa1, wh[p][1], c, 0, 0, 0);
        agh[p] = c;
      }
      #pragma unroll
      for (int i = 0; i < 4; ++i) {
        float4 gv = { agh[0][i], agh[1][i], agh[2][i], 0.f };
        *(float4*)&ghl[(kh * 4 + i) * 260 + n * 4] = gv;
      }
    }
    BARRIER();  // B1: ms & ghl visible; xs/ss reads of this phase done

    // ================= PHASE 2 =================
    if (grp == 0) {
      const unsigned short* am = &ms[(lane & 15) * 72];
      short8 ma0 = *(const short8*)(am + kh * 8);
      short8 ma1 = *(const short8*)(am + 32 + kh * 8);
      f32x4 agi[3];
      #pragma unroll
      for (int p = 0; p < 3; ++p) {
        f32x4 c = {0.f, 0.f, 0.f, 0.f};
        c = __builtin_amdgcn_mfma_f32_16x16x32_bf16(ma0, wi[p][0], c, 0, 0, 0);
        c = __builtin_amdgcn_mfma_f32_16x16x32_bf16(ma1, wi[p][1], c, 0, 0, 0);
        agi[p] = c;
      }
      #pragma unroll
      for (int i = 0; i < 4; ++i) {
        const int rr = kh * 4 + i;
        float4 gh4 = *(const float4*)&ghl[rr * 260 + n * 4];
        float gr  = agi[0][i] + gh4.x + bsum01[0];
        float gz  = agi[1][i] + gh4.y + bsum01[1];
        float gni = agi[2][i] + bih2;
        float gnh = gh4.z + bhh2;
        float rg = fsigmoid(gr);
        float zg = fsigmoid(gz);
        float ng = ftanh(fmaf(rg, gnh, gni));
        float sn = fmaf(zg, s_reg[i] - ng, ng);
        s_reg[i] = sn;
        ss[rr * 72 + n] = f2bf(sn);
        // direct out store (rides across raw barriers; 64B segments x4 per inst)
        out[((size_t)t * NROW + row0 + rr) * DD + n] = sn;
      }
    }
    // G1: nothing in phase 2
    BARRIER();  // B2: ss updated for next step
  }
}

extern "C" void kernel_launch(void* const* d_in, const int* in_sizes, int n_in,
                              void* d_out, int out_size, void* d_ws, size_t ws_size,
                              hipStream_t stream) {
  const float* x      = (const float*)d_in[0];
  const int*   mask   = (const int*)  d_in[1];
  const float* msg_W  = (const float*)d_in[2];
  const float* msg_b  = (const float*)d_in[3];
  const float* W_ih   = (const float*)d_in[4];
  const float* W_hh   = (const float*)d_in[5];
  const float* b_ih   = (const float*)d_in[6];
  const float* b_hh   = (const float*)d_in[7];
  const float* freq   = (const float*)d_in[8];
  const float* phase  = (const float*)d_in[9];
  float* out    = (float*)d_out;
  float* bias_t = (float*)d_ws;   // TT*DD floats = 64 KB

  (void)in_sizes; (void)n_in; (void)out_size; (void)ws_size;

  bias_kernel<<<TT, DD, 0, stream>>>(msg_W, msg_b, freq, phase, bias_t);
  scan5<<<GRID, BLK, 0, stream>>>(x, mask, msg_W, W_ih, W_hh,
                                  b_ih, b_hh, bias_t, out);
}